// Round 1
// baseline (40758.801 us; speedup 1.0000x reference)
//
#include <hip/hip_runtime.h>
#include <cstdint>
#include <cstddef>

// Problem dims
#define TT   1024
#define BB   128
#define FEAT 138
#define FPAD 160          // F padded to multiple of 32 for K-tiling
#define HH   1024
#define G4   4096         // 4*H gate rows
#define VV   128
#define MM   128          // MLP hidden
#define K1   (FPAD + HH)  // 1184: [x | h1prev] concatenated K for LSTM1
#define K2   (2 * HH)     // 2048: [h1 | h2prev] concatenated K for LSTM2

typedef __bf16 bf16x8 __attribute__((ext_vector_type(8)));
typedef float  f32x4  __attribute__((ext_vector_type(4)));
typedef unsigned short u16;

__device__ __forceinline__ u16 f2bf(float f) {  // RNE float->bf16
  uint32_t u = __float_as_uint(f);
  u += 0x7fffu + ((u >> 16) & 1u);
  return (u16)(u >> 16);
}
__device__ __forceinline__ float sigm(float x) { return 1.0f / (1.0f + __expf(-x)); }
__device__ __forceinline__ float tanh_(float x) {
  float e = __expf(-2.0f * fabsf(x));           // e in (0,1]: no inf/NaN
  float t = (1.0f - e) / (1.0f + e);
  return x < 0.0f ? -t : t;
}

// ---------------- prep kernels (run every call; ~150us total) ----------------

// W1cat[r][k] : k<160 -> W_ih1 (padded), else W_hh1.  bf16, K-major.
__global__ void conv_w1cat(const float* __restrict__ Wih, const float* __restrict__ Whh,
                           u16* __restrict__ dst) {
  int r = blockIdx.x;
  for (int k = threadIdx.x; k < K1; k += 256) {
    float v;
    if (k < FPAD) v = (k < FEAT) ? Wih[(size_t)r * FEAT + k] : 0.0f;
    else          v = Whh[(size_t)r * HH + (k - FPAD)];
    dst[(size_t)r * K1 + k] = f2bf(v);
  }
}
// W2cat[r][k] : k<1024 -> W_ih2, else W_hh2.
__global__ void conv_w2cat(const float* __restrict__ Wih, const float* __restrict__ Whh,
                           u16* __restrict__ dst) {
  int r = blockIdx.x;
  for (int k = threadIdx.x; k < K2; k += 256) {
    float v = (k < HH) ? Wih[(size_t)r * HH + k] : Whh[(size_t)r * HH + (k - HH)];
    dst[(size_t)r * K2 + k] = f2bf(v);
  }
}
__global__ void conv_mlp(const float* __restrict__ W1, const float* __restrict__ W2,
                         u16* __restrict__ A, u16* __restrict__ Bm) {
  int i = blockIdx.x * 256 + threadIdx.x;          // 576*256 = 131072 + 16384
  if (i < MM * HH) A[i] = f2bf(W1[i]);
  else {
    int j = i - MM * HH;
    if (j < VV * MM) Bm[j] = f2bf(W2[j]);
  }
}
// x[t][b][0:138] -> bf16 padded [t][b][0:160]
__global__ void conv_x(const float* __restrict__ x, u16* __restrict__ Xb) {
  int tb = blockIdx.x;                              // T*B blocks
  int k = threadIdx.x;
  if (k < FPAD)
    Xb[(size_t)tb * FPAD + k] = (k < FEAT) ? f2bf(x[(size_t)tb * FEAT + k]) : (u16)0;
}
__global__ void zero_ws(uint4* __restrict__ p) {    // 512 blocks * 256 thr * 16B = 2MB
  p[(size_t)blockIdx.x * 256 + threadIdx.x] = uint4{0, 0, 0, 0};
}

// ---------------- phase kernel ----------------
// Block roles per phase k:  [0,128): LSTM1 step k   [128,256): LSTM2 step k-1
//                           [256,264): MLP step k-2
// Kernel-launch boundary provides the device-wide sync between phases.

__device__ __forceinline__ void lstm_block(
    const u16* __restrict__ Wcat, int len0,                 // B-operand seg0 length
    const u16* __restrict__ src0, int ld0,                  // [B][ld0] bf16, k-contig
    const u16* __restrict__ src1, int ld1, int len1,
    float* __restrict__ cbuf,                               // [H][B] fp32
    u16* __restrict__ hout,                                 // [B][H] bf16
    const float* __restrict__ ba, const float* __restrict__ bb,
    int hc0, int bs, float* __restrict__ gall, int tid, int Ktot)
{
  const int wave = tid >> 6, lane = tid & 63;
  const int quad = lane >> 4, l16 = lane & 15;
  const int koff = quad * 8;
  // A: 16 gate rows (gate = wave), lane m = l16, k-contig rows in Wcat
  const u16* arow = Wcat + (size_t)(wave * HH + hc0 + l16) * Ktot + koff;
  // B: batch rows, lane n = l16 (per 16-wide n-tile), 4 n-tiles cover 64 batch
  const u16* b0p = src0 + (size_t)(bs + l16) * ld0 + koff;
  const u16* b1p = src1 + (size_t)(bs + l16) * ld1 + koff;
  const size_t s0 = (size_t)16 * ld0, s1 = (size_t)16 * ld1;

  f32x4 acc0 = {0,0,0,0}, acc1 = {0,0,0,0}, acc2 = {0,0,0,0}, acc3 = {0,0,0,0};
#pragma unroll 2
  for (int kk = 0; kk < len0; kk += 32) {
    bf16x8 a  = *(const bf16x8*)(arow + kk);
    bf16x8 b0 = *(const bf16x8*)(b0p + kk);
    bf16x8 b1 = *(const bf16x8*)(b0p + s0 + kk);
    bf16x8 b2 = *(const bf16x8*)(b0p + 2 * s0 + kk);
    bf16x8 b3 = *(const bf16x8*)(b0p + 3 * s0 + kk);
    acc0 = __builtin_amdgcn_mfma_f32_16x16x32_bf16(a, b0, acc0, 0, 0, 0);
    acc1 = __builtin_amdgcn_mfma_f32_16x16x32_bf16(a, b1, acc1, 0, 0, 0);
    acc2 = __builtin_amdgcn_mfma_f32_16x16x32_bf16(a, b2, acc2, 0, 0, 0);
    acc3 = __builtin_amdgcn_mfma_f32_16x16x32_bf16(a, b3, acc3, 0, 0, 0);
  }
  const u16* arow1 = arow + len0;
#pragma unroll 2
  for (int kk = 0; kk < len1; kk += 32) {
    bf16x8 a  = *(const bf16x8*)(arow1 + kk);
    bf16x8 b0 = *(const bf16x8*)(b1p + kk);
    bf16x8 b1 = *(const bf16x8*)(b1p + s1 + kk);
    bf16x8 b2 = *(const bf16x8*)(b1p + 2 * s1 + kk);
    bf16x8 b3 = *(const bf16x8*)(b1p + 3 * s1 + kk);
    acc0 = __builtin_amdgcn_mfma_f32_16x16x32_bf16(a, b0, acc0, 0, 0, 0);
    acc1 = __builtin_amdgcn_mfma_f32_16x16x32_bf16(a, b1, acc1, 0, 0, 0);
    acc2 = __builtin_amdgcn_mfma_f32_16x16x32_bf16(a, b2, acc2, 0, 0, 0);
    acc3 = __builtin_amdgcn_mfma_f32_16x16x32_bf16(a, b3, acc3, 0, 0, 0);
  }

  // D layout: col = lane&15 (n), row = quad*4+reg (m). Exchange gates via LDS.
  float* gw = gall + wave * 1024;
  const int mrow = quad * 4;
#pragma unroll
  for (int r = 0; r < 4; ++r) {
    gw[(mrow + r) * 64 +      l16] = acc0[r];
    gw[(mrow + r) * 64 + 16 + l16] = acc1[r];
    gw[(mrow + r) * 64 + 32 + l16] = acc2[r];
    gw[(mrow + r) * 64 + 48 + l16] = acc3[r];
  }
  __syncthreads();

  // Elementwise cell update: 16 m x 64 n; each thread does 2x2 (m pairs for u32 h-stores)
  const int n = tid & 63, mp = tid >> 2 >> 4;  // mp = tid>>6, 0..3
  const int b = bs + n;
#pragma unroll
  for (int it = 0; it < 2; ++it) {
    int m0 = it * 8 + mp * 2;
    u16 hv[2];
#pragma unroll
    for (int d = 0; d < 2; ++d) {
      int m = m0 + d;
      int hc = hc0 + m;
      float gi = gall[0 * 1024 + m * 64 + n] + ba[hc]          + bb[hc];
      float gf = gall[1 * 1024 + m * 64 + n] + ba[HH + hc]     + bb[HH + hc];
      float gg = gall[2 * 1024 + m * 64 + n] + ba[2 * HH + hc] + bb[2 * HH + hc];
      float go = gall[3 * 1024 + m * 64 + n] + ba[3 * HH + hc] + bb[3 * HH + hc];
      float iv = sigm(gi), fv = sigm(gf), gv = tanh_(gg), ov = sigm(go);
      float cv = fv * cbuf[(size_t)hc * BB + b] + iv * gv;     // c stays fp32
      cbuf[(size_t)hc * BB + b] = cv;
      hv[d] = f2bf(ov * tanh_(cv));
    }
    *(uint32_t*)(hout + (size_t)b * HH + hc0 + m0) =
        (uint32_t)hv[0] | ((uint32_t)hv[1] << 16);
  }
}

__device__ __forceinline__ void mlp_block(
    const u16* __restrict__ WmA, const u16* __restrict__ WmB,
    const u16* __restrict__ h2src, const float* __restrict__ bm1,
    const float* __restrict__ bm2, float* __restrict__ out,
    int t2, int bs, u16* __restrict__ mid, int tid)
{
  const int wave = tid >> 6, lane = tid & 63, quad = lane >> 4, l16 = lane & 15;
  const int koff = quad * 8;
  const u16* brow = h2src + (size_t)(bs + l16) * HH + koff;
  const u16* a0r = WmA + (size_t)(wave * 32 + l16) * HH + koff;
  const u16* a1r = WmA + (size_t)(wave * 32 + 16 + l16) * HH + koff;
  f32x4 acc0 = {0,0,0,0}, acc1 = {0,0,0,0};
#pragma unroll 2
  for (int kk = 0; kk < HH; kk += 32) {
    bf16x8 b  = *(const bf16x8*)(brow + kk);
    bf16x8 x0 = *(const bf16x8*)(a0r + kk);
    bf16x8 x1 = *(const bf16x8*)(a1r + kk);
    acc0 = __builtin_amdgcn_mfma_f32_16x16x32_bf16(x0, b, acc0, 0, 0, 0);
    acc1 = __builtin_amdgcn_mfma_f32_16x16x32_bf16(x1, b, acc1, 0, 0, 0);
  }
  const float SC = 1.0507009873554804934193349852946f;
  const float AL = 1.6732632423543772848170429916717f;
#pragma unroll
  for (int mt = 0; mt < 2; ++mt) {
    f32x4 ac = mt ? acc1 : acc0;
#pragma unroll
    for (int r = 0; r < 4; ++r) {
      int m = wave * 32 + mt * 16 + quad * 4 + r;
      float v = ac[r] + bm1[m];
      v = v > 0.0f ? SC * v : SC * AL * (__expf(v) - 1.0f);    // SELU
      mid[l16 * MM + m] = f2bf(v);                             // [b][m], m-contig
    }
  }
  __syncthreads();
  const u16* c0r = WmB + (size_t)(wave * 32 + l16) * MM + koff;
  const u16* c1r = WmB + (size_t)(wave * 32 + 16 + l16) * MM + koff;
  const u16* mrow = mid + l16 * MM + koff;
  f32x4 o0 = {0,0,0,0}, o1 = {0,0,0,0};
#pragma unroll
  for (int kk = 0; kk < MM; kk += 32) {
    bf16x8 b  = *(const bf16x8*)(mrow + kk);
    bf16x8 x0 = *(const bf16x8*)(c0r + kk);
    bf16x8 x1 = *(const bf16x8*)(c1r + kk);
    o0 = __builtin_amdgcn_mfma_f32_16x16x32_bf16(x0, b, o0, 0, 0, 0);
    o1 = __builtin_amdgcn_mfma_f32_16x16x32_bf16(x1, b, o1, 0, 0, 0);
  }
  float* orow = out + ((size_t)t2 * BB + bs + l16) * VV;
#pragma unroll
  for (int mt = 0; mt < 2; ++mt) {
    f32x4 ac = mt ? o1 : o0;
    int vb = wave * 32 + mt * 16 + quad * 4;
    float4 o4;
    o4.x = ac[0] + bm2[vb];
    o4.y = ac[1] + bm2[vb + 1];
    o4.z = ac[2] + bm2[vb + 2];
    o4.w = ac[3] + bm2[vb + 3];
    *(float4*)(orow + vb) = o4;
  }
}

__global__ __launch_bounds__(256) void lstm_phase(
    const u16* __restrict__ W1c, const u16* __restrict__ W2c,
    const u16* __restrict__ WmA, const u16* __restrict__ WmB,
    const u16* __restrict__ Xb, u16* __restrict__ h1b, u16* __restrict__ h2b,
    float* __restrict__ c1, float* __restrict__ c2,
    const float* __restrict__ bi1, const float* __restrict__ bh1,
    const float* __restrict__ bi2, const float* __restrict__ bh2,
    const float* __restrict__ bm1, const float* __restrict__ bm2,
    float* __restrict__ out, int ph)
{
  __shared__ float gall[4 * 16 * 64];   // 16KB; reused as 4KB u16 mid[] by MLP
  const int bid = blockIdx.x, tid = threadIdx.x;
  const size_t HB = (size_t)BB * HH;
  if (bid < 128) {                      // LSTM1, t = ph
    if (ph >= TT) return;
    int hc0 = (bid >> 1) * 16, bs = (bid & 1) * 64;
    lstm_block(W1c, FPAD, Xb + (size_t)ph * BB * FPAD, FPAD,
               h1b + (size_t)((ph - 1) & 1) * HB, HH, HH,
               c1, h1b + (size_t)(ph & 1) * HB, bi1, bh1, hc0, bs, gall, tid, K1);
  } else if (bid < 256) {               // LSTM2, t = ph-1
    if (ph < 1 || ph > TT) return;
    int rid = bid - 128;
    int hc0 = (rid >> 1) * 16, bs = (rid & 1) * 64;
    lstm_block(W2c, HH, h1b + (size_t)((ph - 1) & 1) * HB, HH,
               h2b + (size_t)(ph & 1) * HB, HH, HH,
               c2, h2b + (size_t)((ph - 1) & 1) * HB, bi2, bh2, hc0, bs, gall, tid, K2);
  } else {                              // MLP head, t = ph-2
    if (ph < 2) return;
    int bs = (bid - 256) * 16;
    mlp_block(WmA, WmB, h2b + (size_t)(ph & 1) * HB, bm1, bm2, out, ph - 2, bs,
              (u16*)gall, tid);
  }
}

extern "C" void kernel_launch(void* const* d_in, const int* in_sizes, int n_in,
                              void* d_out, int out_size, void* d_ws, size_t ws_size,
                              hipStream_t stream)
{
  const float* x    = (const float*)d_in[0];
  const float* Wih1 = (const float*)d_in[1];
  const float* bih1 = (const float*)d_in[2];
  const float* Whh1 = (const float*)d_in[3];
  const float* bhh1 = (const float*)d_in[4];
  const float* Wih2 = (const float*)d_in[5];
  const float* bih2 = (const float*)d_in[6];
  const float* Whh2 = (const float*)d_in[7];
  const float* bhh2 = (const float*)d_in[8];
  const float* W1   = (const float*)d_in[9];
  const float* b1   = (const float*)d_in[10];
  const float* W2   = (const float*)d_in[11];
  const float* b2   = (const float*)d_in[12];
  float* out = (float*)d_out;
  (void)in_sizes; (void)n_in; (void)out_size;

  char* ws = (char*)d_ws;
  size_t off = 0;
  auto alloc = [&](size_t n) { char* p = ws + off; off += (n + 255) & ~(size_t)255; return p; };
  u16* W1c  = (u16*)alloc((size_t)G4 * K1 * 2);        // 9.70 MB
  u16* W2c  = (u16*)alloc((size_t)G4 * K2 * 2);        // 16.78 MB
  u16* WmAp = (u16*)alloc((size_t)MM * HH * 2);
  u16* WmBp = (u16*)alloc((size_t)VV * MM * 2);
  u16* Xb   = (u16*)alloc((size_t)TT * BB * FPAD * 2); // 41.94 MB
  u16* h1b  = (u16*)alloc(2 * (size_t)BB * HH * 2);    // double-buffered
  u16* h2b  = (u16*)alloc(2 * (size_t)BB * HH * 2);
  float* c1 = (float*)alloc((size_t)HH * BB * 4);
  float* c2 = (float*)alloc((size_t)HH * BB * 4);
  if (ws_size < off) return;  // ~71 MB required

  conv_w1cat<<<G4, 256, 0, stream>>>(Wih1, Whh1, W1c);
  conv_w2cat<<<G4, 256, 0, stream>>>(Wih2, Whh2, W2c);
  conv_mlp<<<576, 256, 0, stream>>>(W1, W2, WmAp, WmBp);
  conv_x<<<TT * BB, 256, 0, stream>>>(x, Xb);
  zero_ws<<<512, 256, 0, stream>>>((uint4*)h1b);       // h1b,h2b,c1,c2 contiguous 2MB

  for (int ph = 0; ph <= TT + 1; ++ph)
    lstm_phase<<<264, 256, 0, stream>>>(W1c, W2c, WmAp, WmBp, Xb, h1b, h2b, c1, c2,
                                        bih1, bhh1, bih2, bhh2, b1, b2, out, ph);
}